// Round 5
// baseline (893.889 us; speedup 1.0000x reference)
//
#include <hip/hip_runtime.h>

#define DD 64
#define RR 16
#define EPSF 1e-9f
#define NPB 64            // nodes per bucket (dst>>6)
#define BINCH 4096        // edges per bin block

typedef unsigned short ushort_t;
typedef __bf16 bf16x8 __attribute__((ext_vector_type(8)));
typedef float f32x4 __attribute__((ext_vector_type(4)));
union F8 { uint4 u; bf16x8 v; };

__device__ __forceinline__ void fma4(float4& a, const float4& w, float s) {
    a.x = fmaf(w.x, s, a.x); a.y = fmaf(w.y, s, a.y);
    a.z = fmaf(w.z, s, a.z); a.w = fmaf(w.w, s, a.w);
}

__device__ __forceinline__ unsigned f2bf(float f) {
    unsigned u = __float_as_uint(f);
    return (u + 0x7FFFu + ((u >> 16) & 1u)) >> 16;   // RNE
}
__device__ __forceinline__ uint2 pk4(float4 v) {
    return make_uint2(f2bf(v.x) | (f2bf(v.y) << 16),
                      f2bf(v.z) | (f2bf(v.w) << 16));
}
__device__ __forceinline__ float bf_lo(unsigned u) { return __uint_as_float(u << 16); }
__device__ __forceinline__ float bf_hi(unsigned u) { return __uint_as_float(u & 0xFFFF0000u); }

// ---------------- W pre-pack into MFMA B-fragment layout -----------------------
__global__ __launch_bounds__(256) void k_packW(
    const float* __restrict__ W, ushort_t* __restrict__ Wb)
{
    int t = blockIdx.x * 256 + threadIdx.x;
    if (t >= RR * 2 * 4 * 64) return;
    int lane = t & 63;
    int ot = (t >> 6) & 3;
    int kb = (t >> 8) & 1;
    int r  = t >> 9;
    int o  = ot * 16 + (lane & 15);
    int k0 = kb * 32 + (lane >> 4) * 8;
    const float* w = W + ((size_t)r * DD + k0) * DD + o;
    unsigned d[4];
    #pragma unroll
    for (int p = 0; p < 4; ++p)
        d[p] = f2bf(w[(2 * p) * DD]) | (f2bf(w[(2 * p + 1) * DD]) << 16);
    ((uint4*)Wb)[t] = make_uint4(d[0], d[1], d[2], d[3]);
}

// ---------------- MFMA transform: Y[r][n][o] bf16 = x[n][:] @ W[r] -------------
__global__ __launch_bounds__(256) void k_transform_mfma(
    const float* __restrict__ x, const ushort_t* __restrict__ Wb,
    ushort_t* __restrict__ Y, int N)
{
    const int lane = threadIdx.x & 63;
    const int m0 = (blockIdx.x * 4 + (threadIdx.x >> 6)) * 16;
    if (m0 >= N) return;
    const int quad = lane >> 4, c = lane & 15;

    int node = m0 + c; if (node >= N) node = N - 1;
    const float* xr = x + (size_t)node * DD + quad * 8;
    float4 xa = *(const float4*)xr;
    float4 xb = *(const float4*)(xr + 4);
    float4 xc = *(const float4*)(xr + 32);
    float4 xd = *(const float4*)(xr + 36);
    F8 a0, a1;
    { uint2 p = pk4(xa), q = pk4(xb); a0.u = make_uint4(p.x, p.y, q.x, q.y); }
    { uint2 p = pk4(xc), q = pk4(xd); a1.u = make_uint4(p.x, p.y, q.x, q.y); }

    const uint4* wbp = (const uint4*)Wb + lane;
    const bool full = (m0 + 16 <= N);

    for (int r = 0; r < RR; ++r) {
        ushort_t* yr = Y + ((size_t)r * N + m0) * DD + c;
        #pragma unroll
        for (int ot = 0; ot < 4; ++ot) {
            F8 b0, b1;
            b0.u = wbp[(size_t)(r * 8 + ot) * 64];
            b1.u = wbp[(size_t)(r * 8 + 4 + ot) * 64];
            f32x4 acc = {0.f, 0.f, 0.f, 0.f};
            acc = __builtin_amdgcn_mfma_f32_16x16x32_bf16(a0.v, b0.v, acc, 0, 0, 0);
            acc = __builtin_amdgcn_mfma_f32_16x16x32_bf16(a1.v, b1.v, acc, 0, 0, 0);
            ushort_t* yp = yr + (ot << 4);
            if (full) {
                #pragma unroll
                for (int g = 0; g < 4; ++g)
                    yp[(size_t)(quad * 4 + g) * DD] = (ushort_t)f2bf(acc[g]);
            } else {
                #pragma unroll
                for (int g = 0; g < 4; ++g)
                    if (m0 + quad * 4 + g < N)
                        yp[(size_t)(quad * 4 + g) * DD] = (ushort_t)f2bf(acc[g]);
            }
        }
    }
}

// ---------------- coarse bucket hist + scan + bin ------------------------------

__global__ __launch_bounds__(256) void k_zero_int(int* __restrict__ p, int n)
{
    int i = blockIdx.x * 256 + threadIdx.x;
    if (i < n) p[i] = 0;
}

__global__ __launch_bounds__(256) void k_hist_coarse(
    const int* __restrict__ ei, int* __restrict__ hist, int E, int B)
{
    __shared__ int h[1024];
    for (int i = threadIdx.x; i < B; i += 256) h[i] = 0;
    __syncthreads();
    const int e0 = blockIdx.x * BINCH;
    #pragma unroll 4
    for (int k = 0; k < BINCH / 256; ++k) {
        int e = e0 + k * 256 + threadIdx.x;
        if (e < E) atomicAdd(&h[ei[E + e] >> 6], 1);
    }
    __syncthreads();
    for (int i = threadIdx.x; i < B; i += 256)
        if (h[i]) atomicAdd(&hist[i], h[i]);
}

__global__ __launch_bounds__(256) void k_scan_bucket(
    const int* __restrict__ hist, int* __restrict__ base,
    int* __restrict__ cursor, int B, int E)
{
    __shared__ int sh[256];
    const int t = threadIdx.x;
    int v[4], s = 0;
    #pragma unroll
    for (int k = 0; k < 4; ++k) {
        int i = t * 4 + k;
        v[k] = (i < B) ? hist[i] : 0;
        s += v[k];
    }
    sh[t] = s;
    __syncthreads();
    for (int off = 1; off < 256; off <<= 1) {
        int tmp = (t >= off) ? sh[t - off] : 0;
        __syncthreads();
        sh[t] += tmp;
        __syncthreads();
    }
    int run = sh[t] - s;
    #pragma unroll
    for (int k = 0; k < 4; ++k) {
        int i = t * 4 + k;
        if (i < B) { base[i] = run; cursor[i] = run; }
        run += v[k];
    }
    if (t == 255) base[B] = E;
}

// rec = {src | rt<<16 | (dst&63)<<20, iv}; runs of ~BINCH/B edges per bucket
__global__ __launch_bounds__(256) void k_bin(
    const int* __restrict__ ei, const int* __restrict__ et,
    const float* __restrict__ pl, int* __restrict__ cursor,
    uint2* __restrict__ ep, int E, int B)
{
    __shared__ int hl[1024];
    __shared__ int bl[1024];
    for (int i = threadIdx.x; i < B; i += 256) hl[i] = 0;
    __syncthreads();
    const int e0 = blockIdx.x * BINCH;
    #pragma unroll 4
    for (int k = 0; k < BINCH / 256; ++k) {
        int e = e0 + k * 256 + threadIdx.x;
        if (e < E) atomicAdd(&hl[ei[E + e] >> 6], 1);
    }
    __syncthreads();
    for (int i = threadIdx.x; i < B; i += 256) {
        int c = hl[i];
        bl[i] = c ? atomicAdd(&cursor[i], c) : 0;
        hl[i] = 0;
    }
    __syncthreads();
    #pragma unroll 2
    for (int k = 0; k < BINCH / 256; ++k) {
        int e = e0 + k * 256 + threadIdx.x;
        if (e < E) {
            int dst = ei[E + e];
            int b = dst >> 6;
            int rank = atomicAdd(&hl[b], 1);
            int src = ei[e];
            int rt  = et[e];
            float iv = 1.0f / fmaxf(pl[e], EPSF);
            ep[bl[b] + rank] = make_uint2(
                (unsigned)src | ((unsigned)rt << 16) | ((unsigned)(dst & 63) << 20),
                __float_as_uint(iv));
        }
    }
}

// ---------------- bucket aggregate: LDS fp32 acc + self loop + bias + relu -----
__global__ __launch_bounds__(256) void k_aggregate_b(
    const ushort_t* __restrict__ Y, const int* __restrict__ base,
    const uint2* __restrict__ ep, const int* __restrict__ et,
    const float* __restrict__ pl, const float* __restrict__ bias,
    float* __restrict__ out, int N, int E)
{
    __shared__ float acc[NPB * DD];   // 16 KB
    const int tid = threadIdx.x;
    const int n0 = blockIdx.x * NPB;
    #pragma unroll
    for (int i = tid; i < NPB * DD; i += 256) acc[i] = 0.f;
    __syncthreads();

    const int beg = base[blockIdx.x], end = base[blockIdx.x + 1];
    const int hw = tid >> 5;          // half-wave 0..7
    const int lane = tid & 31;
    for (int p0 = beg + hw * 32; p0 < end; p0 += 256) {
        int cnt = end - p0; if (cnt > 32) cnt = 32;
        unsigned pk = 0, ivb = 0;
        if (lane < cnt) { uint2 m = ep[p0 + lane]; pk = m.x; ivb = m.y; }
        int jj = 0;
        for (; jj + 4 <= cnt; jj += 4) {
            unsigned v[4], pkk[4]; float ivv[4];
            #pragma unroll
            for (int q = 0; q < 4; ++q) {
                pkk[q] = (unsigned)__shfl((int)pk, jj + q, 32);
                ivv[q] = __uint_as_float((unsigned)__shfl((int)ivb, jj + q, 32));
                v[q] = *(const unsigned*)(Y +
                    (((size_t)((pkk[q] >> 16) & 15u)) * N + (pkk[q] & 0xFFFFu)) * DD + 2 * lane);
            }
            #pragma unroll
            for (int q = 0; q < 4; ++q) {
                float* a = &acc[((pkk[q] >> 20) & 63u) * DD + 2 * lane];
                atomicAdd(a,     bf_lo(v[q]) * ivv[q]);
                atomicAdd(a + 1, bf_hi(v[q]) * ivv[q]);
            }
        }
        for (; jj < cnt; ++jj) {
            unsigned pkj = (unsigned)__shfl((int)pk, jj, 32);
            float ivj = __uint_as_float((unsigned)__shfl((int)ivb, jj, 32));
            unsigned v = *(const unsigned*)(Y +
                (((size_t)((pkj >> 16) & 15u)) * N + (pkj & 0xFFFFu)) * DD + 2 * lane);
            float* a = &acc[((pkj >> 20) & 63u) * DD + 2 * lane];
            atomicAdd(a,     bf_lo(v) * ivj);
            atomicAdd(a + 1, bf_hi(v) * ivj);
        }
    }
    __syncthreads();

    // epilogue: 4 threads per node row; self loop + bias + relu
    const int n = n0 + (tid >> 2);
    if (n >= N) return;
    const int c0 = (tid & 3) * 16;
    int rts = et[E + n];
    float ivs = 1.0f / fmaxf(pl[E + n], EPSF);
    const ushort_t* yp = Y + ((size_t)rts * N + n) * DD + c0;
    uint4 u0 = *(const uint4*)yp;
    uint4 u1 = *(const uint4*)(yp + 8);
    unsigned uu[8] = {u0.x, u0.y, u0.z, u0.w, u1.x, u1.y, u1.z, u1.w};
    const float* ar = &acc[(tid >> 2) * DD + c0];
    float* op = out + (size_t)n * DD + c0;
    #pragma unroll
    for (int g = 0; g < 4; ++g) {
        float4 b4 = *(const float4*)(bias + c0 + 4 * g);
        float4 o;
        o.x = fmaxf(ar[4 * g + 0] + bf_lo(uu[2 * g])     * ivs + b4.x, 0.f);
        o.y = fmaxf(ar[4 * g + 1] + bf_hi(uu[2 * g])     * ivs + b4.y, 0.f);
        o.z = fmaxf(ar[4 * g + 2] + bf_lo(uu[2 * g + 1]) * ivs + b4.z, 0.f);
        o.w = fmaxf(ar[4 * g + 3] + bf_hi(uu[2 * g + 1]) * ivs + b4.w, 0.f);
        *(float4*)(op + 4 * g) = o;
    }
}

// ---------------- fallback (chunked, atomic) -----------------------------------

__global__ __launch_bounds__(256) void k_transform(
    const float* __restrict__ x, const float* __restrict__ W,
    ushort_t* __restrict__ Y, int N, int r_base, int r_cnt, int yr_off)
{
    __shared__ float xt[DD * 128];
    __shared__ float ws[DD * DD];
    const int n0 = blockIdx.x * 128;
    const int tid = threadIdx.x;

    #pragma unroll
    for (int c = 0; c < 8; ++c) {
        int idx = c * 256 + tid;
        int n  = idx >> 4;
        int i4 = (idx & 15) << 2;
        int gn = n0 + n;
        float4 v = make_float4(0.f, 0.f, 0.f, 0.f);
        if (gn < N) v = ((const float4*)(x + (size_t)gn * DD))[idx & 15];
        int n4 = n >> 2, nr = n & 3;
        float vv[4] = {v.x, v.y, v.z, v.w};
        #pragma unroll
        for (int k = 0; k < 4; ++k) {
            int i = i4 + k;
            int swz = (i >> 2) & 7;
            xt[i * 128 + (((n4 ^ swz) << 2) | nr)] = vv[k];
        }
    }

    const int j  = tid & 15;
    const int nq = tid >> 4;

    for (int rr = 0; rr < r_cnt; ++rr) {
        const int r = r_base + blockIdx.y * r_cnt + rr;
        __syncthreads();
        {
            const float4* Wv = (const float4*)(W + (size_t)r * DD * DD);
            float4* wv = (float4*)ws;
            #pragma unroll
            for (int c = 0; c < 4; ++c) wv[c * 256 + tid] = Wv[c * 256 + tid];
        }
        __syncthreads();

        float4 acc[8];
        #pragma unroll
        for (int m = 0; m < 8; ++m) acc[m] = make_float4(0.f, 0.f, 0.f, 0.f);

        #pragma unroll 4
        for (int i = 0; i < DD; ++i) {
            const int swz = (i >> 2) & 7;
            const float4 wv = *(const float4*)&ws[i * DD + 4 * j];
            #pragma unroll
            for (int h = 0; h < 2; ++h) {
                const int col4 = (2 * nq + h) ^ swz;
                const float4 xv = *(const float4*)&xt[i * 128 + (col4 << 2)];
                fma4(acc[4 * h + 0], wv, xv.x);
                fma4(acc[4 * h + 1], wv, xv.y);
                fma4(acc[4 * h + 2], wv, xv.z);
                fma4(acc[4 * h + 3], wv, xv.w);
            }
        }

        const size_t ybase = (size_t)(r - yr_off) * N;
        #pragma unroll
        for (int m = 0; m < 8; ++m) {
            int node = n0 + 8 * nq + 4 * (m >> 2) + (m & 3);
            if (node < N)
                *(uint2*)(Y + (ybase + node) * DD + 4 * j) = pk4(acc[m]);
        }
    }
}

__global__ __launch_bounds__(256) void k_edges(
    const int* __restrict__ ei, const int* __restrict__ et,
    const float* __restrict__ pl, const ushort_t* __restrict__ Y,
    float* __restrict__ aggr, int N, int E, int Etot, int rel_filter)
{
    int sub = threadIdx.x >> 5;
    int lane = threadIdx.x & 31;
    int e = blockIdx.x * 8 + sub;
    if (e >= Etot) return;
    int rt = et[e];
    int yrel = rt;
    if (rel_filter >= 0) { if (rt != rel_filter) return; yrel = 0; }
    int src, dst;
    if (e < E) { src = ei[e]; dst = ei[E + e]; }
    else       { src = dst = e - E; }
    float inv = 1.0f / fmaxf(pl[e], EPSF);
    unsigned v = *(const unsigned*)(Y + ((size_t)yrel * N + src) * DD + 2 * lane);
    atomicAdd(&aggr[(size_t)dst * DD + 2 * lane],     bf_lo(v) * inv);
    atomicAdd(&aggr[(size_t)dst * DD + 2 * lane + 1], bf_hi(v) * inv);
}

__global__ __launch_bounds__(256) void k_bias_relu(
    const float* __restrict__ aggr, const float* __restrict__ bias,
    float* __restrict__ out, int N)
{
    int idx = blockIdx.x * 256 + threadIdx.x;
    if (idx >= N * (DD / 4)) return;
    float4 a = ((const float4*)aggr)[idx];
    int o4 = (idx & 15) * 4;
    a.x = fmaxf(a.x + bias[o4 + 0], 0.f);
    a.y = fmaxf(a.y + bias[o4 + 1], 0.f);
    a.z = fmaxf(a.z + bias[o4 + 2], 0.f);
    a.w = fmaxf(a.w + bias[o4 + 3], 0.f);
    ((float4*)out)[idx] = a;
}

__global__ __launch_bounds__(256) void k_zero(float* __restrict__ p, size_t n)
{
    size_t i = (size_t)blockIdx.x * 256 + threadIdx.x;
    size_t stride = (size_t)gridDim.x * 256;
    for (; i < n; i += stride) p[i] = 0.f;
}

extern "C" void kernel_launch(void* const* d_in, const int* in_sizes, int n_in,
                              void* d_out, int out_size, void* d_ws, size_t ws_size,
                              hipStream_t stream)
{
    const float* x  = (const float*)d_in[0];
    const int*   ei = (const int*)d_in[1];
    const int*   et = (const int*)d_in[2];
    const float* pl = (const float*)d_in[3];
    const float* W1 = (const float*)d_in[4];
    const float* b1 = (const float*)d_in[5];
    const float* W2 = (const float*)d_in[6];
    const float* b2 = (const float*)d_in[7];
    float* out = (float*)d_out;

    const int N = in_sizes[0] / DD;
    const int E = in_sizes[1] / 2;
    const size_t ndf = (size_t)N * DD;
    const size_t wb_elems = (size_t)RR * 2 * 4 * 64 * 8;   // 65536 ushorts
    const int B = (N + NPB - 1) / NPB;

    char* wsb = (char*)d_ws;
    ushort_t* Y   = (ushort_t*)wsb;                          // RR*ndf bf16
    float* aggr1  = (float*)(wsb + (size_t)RR * ndf * 2);    // ndf fp32
    ushort_t* Wb1 = (ushort_t*)((char*)aggr1 + ndf * 4);     // 128 KB
    ushort_t* Wb2 = Wb1 + wb_elems;                          // 128 KB
    int* hist     = (int*)(Wb2 + wb_elems);                  // B
    int* base     = hist + B;                                // B+1
    int* cursor   = base + (B + 1);                          // B
    uint2* ep     = (uint2*)(cursor + B);                    // E

    const size_t need_main = (size_t)RR * ndf * 2 + ndf * 4 + wb_elems * 4 +
        ((size_t)B * 3 + 1) * 4 + (size_t)E * 8;
    const bool main_ok = (ws_size >= need_main) && (N <= 65535) && (B <= 1024);

    if (main_ok) {
        const int gBin = (E + BINCH - 1) / BINCH;
        k_packW<<<(RR * 2 * 4 * 64 + 255) / 256, 256, 0, stream>>>(W1, Wb1);
        k_packW<<<(RR * 2 * 4 * 64 + 255) / 256, 256, 0, stream>>>(W2, Wb2);
        k_zero_int<<<(B + 255) / 256, 256, 0, stream>>>(hist, B);
        k_hist_coarse<<<gBin, 256, 0, stream>>>(ei, hist, E, B);
        k_scan_bucket<<<1, 256, 0, stream>>>(hist, base, cursor, B, E);
        k_bin<<<gBin, 256, 0, stream>>>(ei, et, pl, cursor, ep, E, B);

        const int gT = (N + 63) / 64;
        for (int layer = 0; layer < 2; ++layer) {
            const float* xin   = layer ? aggr1 : x;
            const ushort_t* Wb = layer ? Wb2 : Wb1;
            const float* bias  = layer ? b2 : b1;
            float* dest        = layer ? out : aggr1;
            k_transform_mfma<<<gT, 256, 0, stream>>>(xin, Wb, Y, N);
            k_aggregate_b<<<B, 256, 0, stream>>>(Y, base, ep, et, pl,
                                                 bias, dest, N, E);
        }
        return;
    }

    // chunked fallback: Yc = ndf bf16, aggr = ndf fp32
    ushort_t* Yc = (ushort_t*)wsb;
    float* ag    = (float*)(wsb + ndf * 2);
    const int gx     = (N + 127) / 128;
    const int gEdgeT = (E + N + 7) / 8;
    const int gQuad  = (N * (DD / 4) + 255) / 256;
    float* hid = ag;

    for (int layer = 0; layer < 2; ++layer) {
        const float* xin  = layer ? hid : x;
        const float* W    = layer ? W2 : W1;
        const float* bias = layer ? b2 : b1;
        float* aggr       = layer ? out : ag;
        k_zero<<<1024, 256, 0, stream>>>(aggr, ndf);
        for (int r = 0; r < RR; ++r) {
            k_transform<<<dim3(gx, 1), 256, 0, stream>>>(xin, W, Yc, N, r, 1, r);
            k_edges<<<gEdgeT, 256, 0, stream>>>(ei, et, pl, Yc, aggr, N, E, E + N, r);
        }
        k_bias_relu<<<gQuad, 256, 0, stream>>>(aggr, bias, layer ? out : hid, N);
    }
}

// Round 6
// 252.195 us; speedup vs baseline: 3.5444x; 3.5444x over previous
//
#include <hip/hip_runtime.h>

#define DD 64
#define RR 16
#define EPSF 1e-9f
#define NPB 64            // nodes per bucket (dst>>6)
#define BINCH 4096        // edges per bin block

typedef unsigned short ushort_t;
typedef __bf16 bf16x8 __attribute__((ext_vector_type(8)));
typedef float f32x4 __attribute__((ext_vector_type(4)));
union F8 { uint4 u; bf16x8 v; };

__device__ __forceinline__ void fma4(float4& a, const float4& w, float s) {
    a.x = fmaf(w.x, s, a.x); a.y = fmaf(w.y, s, a.y);
    a.z = fmaf(w.z, s, a.z); a.w = fmaf(w.w, s, a.w);
}

__device__ __forceinline__ unsigned f2bf(float f) {
    unsigned u = __float_as_uint(f);
    return (u + 0x7FFFu + ((u >> 16) & 1u)) >> 16;   // RNE
}
__device__ __forceinline__ uint2 pk4(float4 v) {
    return make_uint2(f2bf(v.x) | (f2bf(v.y) << 16),
                      f2bf(v.z) | (f2bf(v.w) << 16));
}
__device__ __forceinline__ float bf_lo(unsigned u) { return __uint_as_float(u << 16); }
__device__ __forceinline__ float bf_hi(unsigned u) { return __uint_as_float(u & 0xFFFF0000u); }

// ---------------- W pre-pack into MFMA B-fragment layout -----------------------
__global__ __launch_bounds__(256) void k_packW(
    const float* __restrict__ W, ushort_t* __restrict__ Wb)
{
    int t = blockIdx.x * 256 + threadIdx.x;
    if (t >= RR * 2 * 4 * 64) return;
    int lane = t & 63;
    int ot = (t >> 6) & 3;
    int kb = (t >> 8) & 1;
    int r  = t >> 9;
    int o  = ot * 16 + (lane & 15);
    int k0 = kb * 32 + (lane >> 4) * 8;
    const float* w = W + ((size_t)r * DD + k0) * DD + o;
    unsigned d[4];
    #pragma unroll
    for (int p = 0; p < 4; ++p)
        d[p] = f2bf(w[(2 * p) * DD]) | (f2bf(w[(2 * p + 1) * DD]) << 16);
    ((uint4*)Wb)[t] = make_uint4(d[0], d[1], d[2], d[3]);
}

// ---------------- MFMA transform: Y[r][n][o] bf16 = x[n][:] @ W[r] -------------
__global__ __launch_bounds__(256) void k_transform_mfma(
    const float* __restrict__ x, const ushort_t* __restrict__ Wb,
    ushort_t* __restrict__ Y, int N)
{
    const int lane = threadIdx.x & 63;
    const int m0 = (blockIdx.x * 4 + (threadIdx.x >> 6)) * 16;
    if (m0 >= N) return;
    const int quad = lane >> 4, c = lane & 15;

    int node = m0 + c; if (node >= N) node = N - 1;
    const float* xr = x + (size_t)node * DD + quad * 8;
    float4 xa = *(const float4*)xr;
    float4 xb = *(const float4*)(xr + 4);
    float4 xc = *(const float4*)(xr + 32);
    float4 xd = *(const float4*)(xr + 36);
    F8 a0, a1;
    { uint2 p = pk4(xa), q = pk4(xb); a0.u = make_uint4(p.x, p.y, q.x, q.y); }
    { uint2 p = pk4(xc), q = pk4(xd); a1.u = make_uint4(p.x, p.y, q.x, q.y); }

    const uint4* wbp = (const uint4*)Wb + lane;
    const bool full = (m0 + 16 <= N);

    for (int r = 0; r < RR; ++r) {
        ushort_t* yr = Y + ((size_t)r * N + m0) * DD + c;
        #pragma unroll
        for (int ot = 0; ot < 4; ++ot) {
            F8 b0, b1;
            b0.u = wbp[(size_t)(r * 8 + ot) * 64];
            b1.u = wbp[(size_t)(r * 8 + 4 + ot) * 64];
            f32x4 acc = {0.f, 0.f, 0.f, 0.f};
            acc = __builtin_amdgcn_mfma_f32_16x16x32_bf16(a0.v, b0.v, acc, 0, 0, 0);
            acc = __builtin_amdgcn_mfma_f32_16x16x32_bf16(a1.v, b1.v, acc, 0, 0, 0);
            ushort_t* yp = yr + (ot << 4);
            if (full) {
                #pragma unroll
                for (int g = 0; g < 4; ++g)
                    yp[(size_t)(quad * 4 + g) * DD] = (ushort_t)f2bf(acc[g]);
            } else {
                #pragma unroll
                for (int g = 0; g < 4; ++g)
                    if (m0 + quad * 4 + g < N)
                        yp[(size_t)(quad * 4 + g) * DD] = (ushort_t)f2bf(acc[g]);
            }
        }
    }
}

// ---------------- coarse bucket hist + scan + bin + in-bucket sort -------------

__global__ __launch_bounds__(256) void k_zero_int(int* __restrict__ p, int n)
{
    int i = blockIdx.x * 256 + threadIdx.x;
    if (i < n) p[i] = 0;
}

__global__ __launch_bounds__(256) void k_hist_coarse(
    const int* __restrict__ ei, int* __restrict__ hist, int E, int B)
{
    __shared__ int h[1024];
    for (int i = threadIdx.x; i < B; i += 256) h[i] = 0;
    __syncthreads();
    const int e0 = blockIdx.x * BINCH;
    #pragma unroll 4
    for (int k = 0; k < BINCH / 256; ++k) {
        int e = e0 + k * 256 + threadIdx.x;
        if (e < E) atomicAdd(&h[ei[E + e] >> 6], 1);
    }
    __syncthreads();
    for (int i = threadIdx.x; i < B; i += 256)
        if (h[i]) atomicAdd(&hist[i], h[i]);
}

__global__ __launch_bounds__(256) void k_scan_bucket(
    const int* __restrict__ hist, int* __restrict__ base,
    int* __restrict__ cursor, int B, int E)
{
    __shared__ int sh[256];
    const int t = threadIdx.x;
    int v[4], s = 0;
    #pragma unroll
    for (int k = 0; k < 4; ++k) {
        int i = t * 4 + k;
        v[k] = (i < B) ? hist[i] : 0;
        s += v[k];
    }
    sh[t] = s;
    __syncthreads();
    for (int off = 1; off < 256; off <<= 1) {
        int tmp = (t >= off) ? sh[t - off] : 0;
        __syncthreads();
        sh[t] += tmp;
        __syncthreads();
    }
    int run = sh[t] - s;
    #pragma unroll
    for (int k = 0; k < 4; ++k) {
        int i = t * 4 + k;
        if (i < B) { base[i] = run; cursor[i] = run; }
        run += v[k];
    }
    if (t == 255) base[B] = E;
}

// rec = {src | rt<<16 | (dst&63)<<20, iv}; runs of ~BINCH/B edges per bucket
__global__ __launch_bounds__(256) void k_bin(
    const int* __restrict__ ei, const int* __restrict__ et,
    const float* __restrict__ pl, int* __restrict__ cursor,
    uint2* __restrict__ ep, int E, int B)
{
    __shared__ int hl[1024];
    __shared__ int bl[1024];
    for (int i = threadIdx.x; i < B; i += 256) hl[i] = 0;
    __syncthreads();
    const int e0 = blockIdx.x * BINCH;
    #pragma unroll 4
    for (int k = 0; k < BINCH / 256; ++k) {
        int e = e0 + k * 256 + threadIdx.x;
        if (e < E) atomicAdd(&hl[ei[E + e] >> 6], 1);
    }
    __syncthreads();
    for (int i = threadIdx.x; i < B; i += 256) {
        int c = hl[i];
        bl[i] = c ? atomicAdd(&cursor[i], c) : 0;
        hl[i] = 0;
    }
    __syncthreads();
    #pragma unroll 2
    for (int k = 0; k < BINCH / 256; ++k) {
        int e = e0 + k * 256 + threadIdx.x;
        if (e < E) {
            int dst = ei[E + e];
            int b = dst >> 6;
            int rank = atomicAdd(&hl[b], 1);
            int src = ei[e];
            int rt  = et[e];
            float iv = 1.0f / fmaxf(pl[e], EPSF);
            ep[bl[b] + rank] = make_uint2(
                (unsigned)src | ((unsigned)rt << 16) | ((unsigned)(dst & 63) << 20),
                __float_as_uint(iv));
        }
    }
}

// counting-sort each bucket's records into per-node order; emit ep2 + rowptr
__global__ __launch_bounds__(256) void k_sortb(
    const uint2* __restrict__ ep, const int* __restrict__ base,
    uint2* __restrict__ ep2, int* __restrict__ rowptr, int N, int B)
{
    __shared__ int hist[NPB];
    __shared__ int off[NPB];
    const int b = blockIdx.x, tid = threadIdx.x;
    const int beg = base[b], end = base[b + 1];
    if (tid < NPB) hist[tid] = 0;
    __syncthreads();
    for (int p = beg + tid; p < end; p += 256)
        atomicAdd(&hist[(ep[p].x >> 20) & 63u], 1);
    __syncthreads();
    if (tid == 0) {                       // tiny 64-wide exclusive scan
        int run = 0;
        #pragma unroll
        for (int i = 0; i < NPB; ++i) { off[i] = run; run += hist[i]; }
    }
    __syncthreads();
    if (tid < NPB) {
        int n = b * NPB + tid;
        if (n <= N) rowptr[n] = beg + off[tid];
        hist[tid] = 0;                    // reuse as rank cursor
    }
    __syncthreads();
    for (int p = beg + tid; p < end; p += 256) {
        uint2 m = ep[p];
        int d = (m.x >> 20) & 63u;
        int rank = atomicAdd(&hist[d], 1);
        ep2[beg + off[d] + rank] = make_uint2(m.x & 0xFFFFFu, m.y);
    }
}

// ---------------- fused aggregate (R4 structure): half-wave per node -----------
__global__ __launch_bounds__(256) void k_aggregate(
    const ushort_t* __restrict__ Y, const int* __restrict__ rowptr,
    const uint2* __restrict__ ep,
    const int* __restrict__ et, const float* __restrict__ pl,
    const float* __restrict__ bias, float* __restrict__ out, int N, int E)
{
    const int n = blockIdx.x * 8 + (threadIdx.x >> 5);
    const int lane = threadIdx.x & 31;
    if (n >= N) return;

    int rts = et[E + n];
    float ivs = 1.0f / fmaxf(pl[E + n], EPSF);
    unsigned yv = *(const unsigned*)(Y + ((size_t)rts * N + n) * DD + 2 * lane);
    float accx = bf_lo(yv) * ivs;
    float accy = bf_hi(yv) * ivs;

    const int beg = rowptr[n], end = rowptr[n + 1];
    for (int p0 = beg; p0 < end; p0 += 32) {
        int cnt = end - p0; if (cnt > 32) cnt = 32;
        unsigned pk = 0, ivb = 0;
        if (lane < cnt) { uint2 m = ep[p0 + lane]; pk = m.x; ivb = m.y; }
        int jj = 0;
        for (; jj + 4 <= cnt; jj += 4) {
            unsigned v[4]; float ivv[4];
            #pragma unroll
            for (int q = 0; q < 4; ++q) {
                unsigned pkj = (unsigned)__shfl((int)pk, jj + q, 32);
                ivv[q] = __uint_as_float((unsigned)__shfl((int)ivb, jj + q, 32));
                v[q] = *(const unsigned*)(Y +
                    (((size_t)((pkj >> 16) & 15u)) * N + (pkj & 0xFFFFu)) * DD + 2 * lane);
            }
            #pragma unroll
            for (int q = 0; q < 4; ++q) {
                accx = fmaf(bf_lo(v[q]), ivv[q], accx);
                accy = fmaf(bf_hi(v[q]), ivv[q], accy);
            }
        }
        for (; jj < cnt; ++jj) {
            unsigned pkj = (unsigned)__shfl((int)pk, jj, 32);
            float ivj = __uint_as_float((unsigned)__shfl((int)ivb, jj, 32));
            unsigned v = *(const unsigned*)(Y +
                (((size_t)((pkj >> 16) & 15u)) * N + (pkj & 0xFFFFu)) * DD + 2 * lane);
            accx = fmaf(bf_lo(v), ivj, accx);
            accy = fmaf(bf_hi(v), ivj, accy);
        }
    }
    float2 bb = *(const float2*)(bias + 2 * lane);
    float2 o;
    o.x = fmaxf(accx + bb.x, 0.f);
    o.y = fmaxf(accy + bb.y, 0.f);
    *(float2*)(out + (size_t)n * DD + 2 * lane) = o;
}

// ---------------- fallback (chunked, atomic) -----------------------------------

__global__ __launch_bounds__(256) void k_transform(
    const float* __restrict__ x, const float* __restrict__ W,
    ushort_t* __restrict__ Y, int N, int r_base, int r_cnt, int yr_off)
{
    __shared__ float xt[DD * 128];
    __shared__ float ws[DD * DD];
    const int n0 = blockIdx.x * 128;
    const int tid = threadIdx.x;

    #pragma unroll
    for (int c = 0; c < 8; ++c) {
        int idx = c * 256 + tid;
        int n  = idx >> 4;
        int i4 = (idx & 15) << 2;
        int gn = n0 + n;
        float4 v = make_float4(0.f, 0.f, 0.f, 0.f);
        if (gn < N) v = ((const float4*)(x + (size_t)gn * DD))[idx & 15];
        int n4 = n >> 2, nr = n & 3;
        float vv[4] = {v.x, v.y, v.z, v.w};
        #pragma unroll
        for (int k = 0; k < 4; ++k) {
            int i = i4 + k;
            int swz = (i >> 2) & 7;
            xt[i * 128 + (((n4 ^ swz) << 2) | nr)] = vv[k];
        }
    }

    const int j  = tid & 15;
    const int nq = tid >> 4;

    for (int rr = 0; rr < r_cnt; ++rr) {
        const int r = r_base + blockIdx.y * r_cnt + rr;
        __syncthreads();
        {
            const float4* Wv = (const float4*)(W + (size_t)r * DD * DD);
            float4* wv = (float4*)ws;
            #pragma unroll
            for (int c = 0; c < 4; ++c) wv[c * 256 + tid] = Wv[c * 256 + tid];
        }
        __syncthreads();

        float4 acc[8];
        #pragma unroll
        for (int m = 0; m < 8; ++m) acc[m] = make_float4(0.f, 0.f, 0.f, 0.f);

        #pragma unroll 4
        for (int i = 0; i < DD; ++i) {
            const int swz = (i >> 2) & 7;
            const float4 wv = *(const float4*)&ws[i * DD + 4 * j];
            #pragma unroll
            for (int h = 0; h < 2; ++h) {
                const int col4 = (2 * nq + h) ^ swz;
                const float4 xv = *(const float4*)&xt[i * 128 + (col4 << 2)];
                fma4(acc[4 * h + 0], wv, xv.x);
                fma4(acc[4 * h + 1], wv, xv.y);
                fma4(acc[4 * h + 2], wv, xv.z);
                fma4(acc[4 * h + 3], wv, xv.w);
            }
        }

        const size_t ybase = (size_t)(r - yr_off) * N;
        #pragma unroll
        for (int m = 0; m < 8; ++m) {
            int node = n0 + 8 * nq + 4 * (m >> 2) + (m & 3);
            if (node < N)
                *(uint2*)(Y + (ybase + node) * DD + 4 * j) = pk4(acc[m]);
        }
    }
}

__global__ __launch_bounds__(256) void k_edges(
    const int* __restrict__ ei, const int* __restrict__ et,
    const float* __restrict__ pl, const ushort_t* __restrict__ Y,
    float* __restrict__ aggr, int N, int E, int Etot, int rel_filter)
{
    int sub = threadIdx.x >> 5;
    int lane = threadIdx.x & 31;
    int e = blockIdx.x * 8 + sub;
    if (e >= Etot) return;
    int rt = et[e];
    int yrel = rt;
    if (rel_filter >= 0) { if (rt != rel_filter) return; yrel = 0; }
    int src, dst;
    if (e < E) { src = ei[e]; dst = ei[E + e]; }
    else       { src = dst = e - E; }
    float inv = 1.0f / fmaxf(pl[e], EPSF);
    unsigned v = *(const unsigned*)(Y + ((size_t)yrel * N + src) * DD + 2 * lane);
    atomicAdd(&aggr[(size_t)dst * DD + 2 * lane],     bf_lo(v) * inv);
    atomicAdd(&aggr[(size_t)dst * DD + 2 * lane + 1], bf_hi(v) * inv);
}

__global__ __launch_bounds__(256) void k_bias_relu(
    const float* __restrict__ aggr, const float* __restrict__ bias,
    float* __restrict__ out, int N)
{
    int idx = blockIdx.x * 256 + threadIdx.x;
    if (idx >= N * (DD / 4)) return;
    float4 a = ((const float4*)aggr)[idx];
    int o4 = (idx & 15) * 4;
    a.x = fmaxf(a.x + bias[o4 + 0], 0.f);
    a.y = fmaxf(a.y + bias[o4 + 1], 0.f);
    a.z = fmaxf(a.z + bias[o4 + 2], 0.f);
    a.w = fmaxf(a.w + bias[o4 + 3], 0.f);
    ((float4*)out)[idx] = a;
}

__global__ __launch_bounds__(256) void k_zero(float* __restrict__ p, size_t n)
{
    size_t i = (size_t)blockIdx.x * 256 + threadIdx.x;
    size_t stride = (size_t)gridDim.x * 256;
    for (; i < n; i += stride) p[i] = 0.f;
}

extern "C" void kernel_launch(void* const* d_in, const int* in_sizes, int n_in,
                              void* d_out, int out_size, void* d_ws, size_t ws_size,
                              hipStream_t stream)
{
    const float* x  = (const float*)d_in[0];
    const int*   ei = (const int*)d_in[1];
    const int*   et = (const int*)d_in[2];
    const float* pl = (const float*)d_in[3];
    const float* W1 = (const float*)d_in[4];
    const float* b1 = (const float*)d_in[5];
    const float* W2 = (const float*)d_in[6];
    const float* b2 = (const float*)d_in[7];
    float* out = (float*)d_out;

    const int N = in_sizes[0] / DD;
    const int E = in_sizes[1] / 2;
    const size_t ndf = (size_t)N * DD;
    const size_t wb_elems = (size_t)RR * 2 * 4 * 64 * 8;   // 65536 ushorts
    const int B = (N + NPB - 1) / NPB;

    char* wsb = (char*)d_ws;
    ushort_t* Y   = (ushort_t*)wsb;                          // RR*ndf bf16
    float* aggr1  = (float*)(wsb + (size_t)RR * ndf * 2);    // ndf fp32
    ushort_t* Wb1 = (ushort_t*)((char*)aggr1 + ndf * 4);     // 128 KB
    ushort_t* Wb2 = Wb1 + wb_elems;                          // 128 KB
    uint2* ep     = (uint2*)(Wb2 + wb_elems);                // E   (8B aligned)
    uint2* ep2    = ep + E;                                  // E
    int* hist     = (int*)(ep2 + E);                         // B
    int* base     = hist + B;                                // B+1
    int* cursor   = base + (B + 1);                          // B
    int* rowptr   = cursor + B;                              // N+1

    const size_t need_main = (size_t)RR * ndf * 2 + ndf * 4 + wb_elems * 4 +
        (size_t)E * 16 + ((size_t)B * 3 + 1 + (size_t)N + 1) * 4;
    const bool main_ok = (ws_size >= need_main) && (N <= 65535) && (B <= 1024);

    if (main_ok) {
        const int gBin = (E + BINCH - 1) / BINCH;
        k_packW<<<(RR * 2 * 4 * 64 + 255) / 256, 256, 0, stream>>>(W1, Wb1);
        k_packW<<<(RR * 2 * 4 * 64 + 255) / 256, 256, 0, stream>>>(W2, Wb2);
        k_zero_int<<<(B + 255) / 256, 256, 0, stream>>>(hist, B);
        k_hist_coarse<<<gBin, 256, 0, stream>>>(ei, hist, E, B);
        k_scan_bucket<<<1, 256, 0, stream>>>(hist, base, cursor, B, E);
        k_bin<<<gBin, 256, 0, stream>>>(ei, et, pl, cursor, ep, E, B);
        k_sortb<<<B, 256, 0, stream>>>(ep, base, ep2, rowptr, N, B);

        const int gT = (N + 63) / 64;
        const int gA = (N + 7) / 8;
        for (int layer = 0; layer < 2; ++layer) {
            const float* xin   = layer ? aggr1 : x;
            const ushort_t* Wb = layer ? Wb2 : Wb1;
            const float* bias  = layer ? b2 : b1;
            float* dest        = layer ? out : aggr1;
            k_transform_mfma<<<gT, 256, 0, stream>>>(xin, Wb, Y, N);
            k_aggregate<<<gA, 256, 0, stream>>>(Y, rowptr, ep2, et, pl,
                                                bias, dest, N, E);
        }
        return;
    }

    // chunked fallback: Yc = ndf bf16, aggr = ndf fp32
    ushort_t* Yc = (ushort_t*)wsb;
    float* ag    = (float*)(wsb + ndf * 2);
    const int gx     = (N + 127) / 128;
    const int gEdgeT = (E + N + 7) / 8;
    const int gQuad  = (N * (DD / 4) + 255) / 256;
    float* hid = ag;

    for (int layer = 0; layer < 2; ++layer) {
        const float* xin  = layer ? hid : x;
        const float* W    = layer ? W2 : W1;
        const float* bias = layer ? b2 : b1;
        float* aggr       = layer ? out : ag;
        k_zero<<<1024, 256, 0, stream>>>(aggr, ndf);
        for (int r = 0; r < RR; ++r) {
            k_transform<<<dim3(gx, 1), 256, 0, stream>>>(xin, W, Yc, N, r, 1, r);
            k_edges<<<gEdgeT, 256, 0, stream>>>(ei, et, pl, Yc, aggr, N, E, E + N, r);
        }
        k_bias_relu<<<gQuad, 256, 0, stream>>>(aggr, bias, layer ? out : hid, N);
    }
}